// Round 10
// baseline (502.761 us; speedup 1.0000x reference)
//
#include <hip/hip_runtime.h>
#include <stdint.h>

// Problem constants
#define T_    256
#define B_    4
#define U_    64
#define EENC  1024
#define EDEC  640
#define J_    640
#define V_    4096

typedef unsigned short u16;
typedef unsigned int   u32;
typedef __bf16 bf16x8 __attribute__((ext_vector_type(8)));
typedef short  s16x8  __attribute__((ext_vector_type(8)));
typedef float  f32x4  __attribute__((ext_vector_type(4)));

__device__ __forceinline__ u16 f2bf(float f) {
    u32 u = __builtin_bit_cast(u32, f);
    u = (u + 0x7FFFu + ((u >> 16) & 1u)) >> 16;
    return (u16)u;
}
__device__ __forceinline__ float bf2f(u16 b) {
    return __builtin_bit_cast(float, (u32)b << 16);
}

// ---------------- f32 -> bf16 convert (vectorized x4) ----------------
__global__ __launch_bounds__(256) void cvt_bf16(const float* __restrict__ src,
                                                u16* __restrict__ dst, int n4) {
    int i = blockIdx.x * 256 + threadIdx.x;
    if (i < n4) {
        float4 v = reinterpret_cast<const float4*>(src)[i];
        ushort4 o;
        o.x = f2bf(v.x); o.y = f2bf(v.y); o.z = f2bf(v.z); o.w = f2bf(v.w);
        reinterpret_cast<ushort4*>(dst)[i] = o;
    }
}

// ---------------- LayerNorm over J=640 + bias + affine, bf16 out, transposed ----------------
__global__ __launch_bounds__(256) void ln_kernel(const float* __restrict__ proj,
                                                 const float* __restrict__ bias,
                                                 const float* __restrict__ gamma,
                                                 const float* __restrict__ beta,
                                                 u16* __restrict__ out,
                                                 int BDIM, int OUTER) {
    int pr = blockIdx.x;
    int b = pr % BDIM, outer = pr / BDIM;
    const float* row = proj + (size_t)pr * J_;
    int tid = threadIdx.x;

    float x0 = row[tid] + bias[tid];
    float x1 = row[tid + 256] + bias[tid + 256];
    float x2 = 0.f;
    bool has3 = (tid < J_ - 512);
    if (has3) x2 = row[tid + 512] + bias[tid + 512];

    float s1 = x0 + x1 + x2;
    float s2 = x0 * x0 + x1 * x1 + x2 * x2;
    for (int off = 32; off; off >>= 1) {
        s1 += __shfl_down(s1, off, 64);
        s2 += __shfl_down(s2, off, 64);
    }
    __shared__ float ws1[4], ws2[4];
    int w = tid >> 6, lane = tid & 63;
    if (lane == 0) { ws1[w] = s1; ws2[w] = s2; }
    __syncthreads();
    float S1 = ws1[0] + ws1[1] + ws1[2] + ws1[3];
    float S2 = ws2[0] + ws2[1] + ws2[2] + ws2[3];
    float mu = S1 * (1.f / J_);
    float var = S2 * (1.f / J_) - mu * mu;
    float inv = 1.0f / sqrtf(var + 1e-5f);

    size_t orow = ((size_t)b * OUTER + outer) * J_;
    out[orow + tid]       = f2bf((x0 - mu) * inv * gamma[tid]       + beta[tid]);
    out[orow + tid + 256] = f2bf((x1 - mu) * inv * gamma[tid + 256] + beta[tid + 256]);
    if (has3)
        out[orow + tid + 512] = f2bf((x2 - mu) * inv * gamma[tid + 512] + beta[tid + 512]);
}

// ---------------- joint materialization: relu(enc[b,t,:] + dec[b,u,:]) -> bf16 [B*T*U][J] ----------------
__global__ __launch_bounds__(256) void joint_mat(const u16* __restrict__ encln,
                                                 const u16* __restrict__ decln,
                                                 u16* __restrict__ joint) {
    int g = blockIdx.x * 256 + threadIdx.x;
    int row = g / (J_ / 8);
    int jc = g - row * (J_ / 8);
    int b = row >> 14;
    int t = (row >> 6) & (T_ - 1);
    int u = row & (U_ - 1);
    s16x8 e = *reinterpret_cast<const s16x8*>(encln + ((size_t)(b * T_ + t)) * J_ + jc * 8);
    s16x8 d = *reinterpret_cast<const s16x8*>(decln + ((size_t)(b * U_ + u)) * J_ + jc * 8);
    s16x8 o;
#pragma unroll
    for (int k = 0; k < 8; ++k) {
        float v = bf2f((u16)e[k]) + bf2f((u16)d[k]);
        o[k] = (short)f2bf(fmaxf(v, 0.f));
    }
    *reinterpret_cast<s16x8*>(joint + (size_t)row * J_ + jc * 8) = o;
}

// ---------------- m97-structure 128x128 GEMM (stage-1 projections) ----------------
__global__ __launch_bounds__(256) void gemm_bt(const u16* __restrict__ A,
                                               const u16* __restrict__ Bt,
                                               float* __restrict__ C,
                                               const float* __restrict__ bias,
                                               int K, int ldc) {
    __shared__ u16 As[128 * 64];
    __shared__ u16 Bs[128 * 64];
    const int tid = threadIdx.x;
    const int w = tid >> 6, lane = tid & 63;
    const int wr = w >> 1, wc = w & 1;
    const size_t m0 = (size_t)blockIdx.y * 128;
    const size_t n0 = (size_t)blockIdx.x * 128;

    f32x4 acc[4][4] = {};

    const int l3 = lane >> 3;
    const int c8 = (lane & 7) * 8;
    const int nkt = K >> 6;

    for (int kt = 0; kt < nkt; ++kt) {
        if (kt) __syncthreads();
        const int k0 = kt << 6;
#pragma unroll
        for (int i = 0; i < 4; ++i) {
            const int c = w * 4 + i;
            const int r = c * 8 + l3;
            const u16* ga = A  + (m0 + r) * (size_t)K + k0 + c8;
            const u16* gb = Bt + (n0 + r) * (size_t)K + k0 + c8;
            __builtin_amdgcn_global_load_lds(
                (const __attribute__((address_space(1))) void*)ga,
                (__attribute__((address_space(3))) void*)(As + c * 512), 16, 0, 0);
            __builtin_amdgcn_global_load_lds(
                (const __attribute__((address_space(1))) void*)gb,
                (__attribute__((address_space(3))) void*)(Bs + c * 512), 16, 0, 0);
        }
        __syncthreads();

#pragma unroll
        for (int kk = 0; kk < 2; ++kk) {
            bf16x8 af[4], bfr[4];
#pragma unroll
            for (int i = 0; i < 4; ++i) {
                int ra = wr * 64 + i * 16 + (lane & 15);
                af[i] = *reinterpret_cast<const bf16x8*>(As + ra * 64 + kk * 32 + (lane >> 4) * 8);
                int rb = wc * 64 + i * 16 + (lane & 15);
                bfr[i] = *reinterpret_cast<const bf16x8*>(Bs + rb * 64 + kk * 32 + (lane >> 4) * 8);
            }
#pragma unroll
            for (int i = 0; i < 4; ++i)
#pragma unroll
                for (int j = 0; j < 4; ++j)
                    acc[i][j] = __builtin_amdgcn_mfma_f32_16x16x32_bf16(af[i], bfr[j], acc[i][j], 0, 0, 0);
        }
    }

    const int r4 = (lane >> 4) * 4;
    const int cl = lane & 15;
#pragma unroll
    for (int i = 0; i < 4; ++i) {
#pragma unroll
        for (int j = 0; j < 4; ++j) {
            size_t grow = m0 + wr * 64 + i * 16 + r4;
            size_t gcol = n0 + wc * 64 + j * 16 + cl;
            float bv = bias ? bias[gcol] : 0.f;
#pragma unroll
            for (int r = 0; r < 4; ++r)
                C[(grow + r) * (size_t)ldc + gcol] = acc[i][j][r] + bv;
        }
    }
}

// ---------------- vocab projection: 128x128 tile, BK=64, conflict-free swizzle ----------------
// R10: K-loop rebuilt on the m201-verified LDS geometry. 128-B rows (BK=64 bf16)
// + 3-bit XOR swizzle (byte ^= (row&7)<<4): each wave's 16-lane row-groups spread
// across all 8 bank segments -> conflict-free ds_read_b128 (m201: 141x conflict
// reduction). Prior BKS=32 layout had 64-B rows -> only 4 segs reachable -> 8-way
// conflicts = the K-loop limiter (R7 staging-depth null, R9 store-path null).
// 256 thr = 4 waves (2x2), wave tile 64x64, acc[4][4]; dbuf LDS 64 KiB -> 2 wg/CU
// (cross-wg overlap of epilogue drain, R6 win). nt direct stores. XCD n-ownership.
#define BK2  64
#define BIGK 640
#define BIGN 4096
#define NT2  (BIGK / BK2)
#define TSZ  (128 * BK2)   // u16 per tile buffer (16 KiB)

__global__ __launch_bounds__(256, 2) void gemm_big(const u16* __restrict__ A,
                                                   const u16* __restrict__ Bt,
                                                   float* __restrict__ C,
                                                   const float* __restrict__ bias) {
    __shared__ u16 Ab[2][TSZ];   // 32 KiB
    __shared__ u16 Bb[2][TSZ];   // 32 KiB

    const int tid = threadIdx.x;
    const int w = tid >> 6, lane = tid & 63;
    const int wr = w >> 1, wc = w & 1;
    const int fr = lane & 15, fq = lane >> 4;

    // XCD n-ownership: xcd owns n-tiles {4*xcd .. 4*xcd+3} (B panel 655 KB, L2-hot);
    // 4 consecutive wgs share one A panel (L2-hot after first).
    const int lin = blockIdx.x;
    const int xcd = lin & 7;
    const int idx = lin >> 3;            // 0..2047
    const size_t m0 = (size_t)(idx >> 2) * 128;
    const size_t n0 = (size_t)(xcd * 4 + (idx & 3)) * 128;

    // staging: call c covers rows [c*32, c*32+32) (32 rows x 128 B = 4 KB).
    // thread -> (row = c*32 + (tid>>3), phys seg = tid&7); source seg pre-swizzled
    // by ^ (row&7) so LDS dest stays linear (gload_lds requirement).
    const int srow = tid >> 3;                     // 0..31
    const int sseg = (tid & 7) ^ (srow & 7);       // (c*32+srow)&7 == srow&7
    const u16* aga = A  + (m0 + srow) * (size_t)BIGK + sseg * 8;
    const u16* bga = Bt + (n0 + srow) * (size_t)BIGK + sseg * 8;

    f32x4 acc[4][4] = {};

#define STAGE(buf, k0)                                                             \
    { _Pragma("unroll")                                                            \
      for (int c = 0; c < 4; ++c) {                                                \
        __builtin_amdgcn_global_load_lds(                                          \
            (const __attribute__((address_space(1))) void*)(aga + (size_t)c * 32 * BIGK + (k0)), \
            (__attribute__((address_space(3))) void*)(&Ab[buf][c * 2048 + tid * 8]), 16, 0, 0);  \
        __builtin_amdgcn_global_load_lds(                                          \
            (const __attribute__((address_space(1))) void*)(bga + (size_t)c * 32 * BIGK + (k0)), \
            (__attribute__((address_space(3))) void*)(&Bb[buf][c * 2048 + tid * 8]), 16, 0, 0);  \
      } }

    // ds_read: logical (row r, seg q = kk*4+fq) -> phys u16 off r*64 + ((q^(r&7))*8)
#define RD_A(buf, mi, kk)                                                          \
    (*reinterpret_cast<const bf16x8*>(&Ab[buf][                                    \
        (wr * 64 + (mi) * 16 + fr) * 64 +                                          \
        ((((kk) * 4 + fq) ^ ((wr * 64 + (mi) * 16 + fr) & 7)) * 8)]))
#define RD_B(buf, ni, kk)                                                          \
    (*reinterpret_cast<const bf16x8*>(&Bb[buf][                                    \
        (wc * 64 + (ni) * 16 + fr) * 64 +                                          \
        ((((kk) * 4 + fq) ^ ((wc * 64 + (ni) * 16 + fr) & 7)) * 8)]))

#define VM0   asm volatile("s_waitcnt vmcnt(0)" ::: "memory")
#define LGKM0 asm volatile("s_waitcnt lgkmcnt(0)" ::: "memory")

    // prologue
    STAGE(0, 0);
    VM0;
    __builtin_amdgcn_s_barrier();

    for (int t = 0; t < NT2; ++t) {
        const int cur = t & 1, nxt = cur ^ 1;
        const bool pf = (t + 1 < NT2);
        bf16x8 af0[4], bf0[4], af1[4], bf1[4];

#pragma unroll
        for (int i = 0; i < 4; ++i) { af0[i] = RD_A(cur, i, 0); }
#pragma unroll
        for (int j = 0; j < 4; ++j) { bf0[j] = RD_B(cur, j, 0); }
#pragma unroll
        for (int i = 0; i < 4; ++i) { af1[i] = RD_A(cur, i, 1); }
#pragma unroll
        for (int j = 0; j < 4; ++j) { bf1[j] = RD_B(cur, j, 1); }
        if (pf) STAGE(nxt, (t + 1) * BK2);     // 8 loads issued under the MFMA phase
        LGKM0;
        __builtin_amdgcn_s_setprio(1);
#pragma unroll
        for (int i = 0; i < 4; ++i)
#pragma unroll
            for (int j = 0; j < 4; ++j)
                acc[i][j] = __builtin_amdgcn_mfma_f32_16x16x32_bf16(af0[i], bf0[j], acc[i][j], 0, 0, 0);
#pragma unroll
        for (int i = 0; i < 4; ++i)
#pragma unroll
            for (int j = 0; j < 4; ++j)
                acc[i][j] = __builtin_amdgcn_mfma_f32_16x16x32_bf16(af1[i], bf1[j], acc[i][j], 0, 0, 0);
        __builtin_amdgcn_s_setprio(0);
        if (pf) {
            VM0;                               // stage loads landed (issued 32 MFMA ago)
            __builtin_amdgcn_s_barrier();
        }
    }

#undef STAGE
#undef RD_A
#undef RD_B
#undef VM0
#undef LGKM0

    // epilogue: nt direct stores (R9 bounce was neutral; keep simple)
    const size_t crow0 = m0 + wr * 64 + fq * 4;
    const size_t ccol0 = n0 + wc * 64 + fr;
#pragma unroll
    for (int ni = 0; ni < 4; ++ni) {
        const size_t col = ccol0 + ni * 16;
        const float bv = bias[col];
#pragma unroll
        for (int mi = 0; mi < 4; ++mi) {
            const size_t rbase = crow0 + mi * 16;
#pragma unroll
            for (int r = 0; r < 4; ++r)
                __builtin_nontemporal_store(acc[mi][ni][r] + bv,
                                            &C[(rbase + r) * (size_t)BIGN + col]);
        }
    }
}

// ---------------- workspace layout (bytes) ----------------
static const size_t O_JOINT = 0;                              // bf16 [65536][640]
static const size_t O_WOUT  = 83886080;                       // bf16 [4096][640]
static const size_t O_ENCLN = 89128960;                       // bf16 [B*T][J]
static const size_t O_DECLN = 90439680;                       // bf16 [B*U][J]
static const size_t O_ENCIN = 90767360;                       // bf16 [T*B][EENC]
static const size_t O_DECIN = 92864512;                       // bf16 [U*B][EDEC]
static const size_t O_WENC  = 93192192;                       // bf16 [J][EENC]
static const size_t O_WDEC  = 94502912;                       // bf16 [J][EDEC]
static const size_t O_EPROJ = 95322112;                       // f32  [T*B][J]
static const size_t O_DPROJ = 97943552;                       // f32  [U*B][J]
static const size_t WS_NEEDED = 98598912;

extern "C" void kernel_launch(void* const* d_in, const int* in_sizes, int n_in,
                              void* d_out, int out_size, void* d_ws, size_t ws_size,
                              hipStream_t stream) {
    const float* enc   = (const float*)d_in[0];
    const float* dec   = (const float*)d_in[1];
    const float* Wenc  = (const float*)d_in[2];
    const float* benc  = (const float*)d_in[3];
    const float* genc  = (const float*)d_in[4];
    const float* beenc = (const float*)d_in[5];
    const float* Wdec  = (const float*)d_in[6];
    const float* bdec  = (const float*)d_in[7];
    const float* gdec  = (const float*)d_in[8];
    const float* bedec = (const float*)d_in[9];
    const float* Wout  = (const float*)d_in[10];
    const float* bout  = (const float*)d_in[11];
    float* out = (float*)d_out;

    if (ws_size < WS_NEEDED) return;

    char* ws = (char*)d_ws;
    u16* joint  = (u16*)(ws + O_JOINT);
    u16* wout_b = (u16*)(ws + O_WOUT);
    u16* encln  = (u16*)(ws + O_ENCLN);
    u16* decln  = (u16*)(ws + O_DECLN);
    u16* encin  = (u16*)(ws + O_ENCIN);
    u16* decin  = (u16*)(ws + O_DECIN);
    u16* wenc_b = (u16*)(ws + O_WENC);
    u16* wdec_b = (u16*)(ws + O_WDEC);
    float* eproj = (float*)(ws + O_EPROJ);
    float* dproj = (float*)(ws + O_DPROJ);

    // 1) bf16 converts
    cvt_bf16<<<1024, 256, 0, stream>>>(enc,  encin,  (T_ * B_ * EENC) / 4);
    cvt_bf16<<<160,  256, 0, stream>>>(dec,  decin,  (U_ * B_ * EDEC) / 4);
    cvt_bf16<<<640,  256, 0, stream>>>(Wenc, wenc_b, (J_ * EENC) / 4);
    cvt_bf16<<<400,  256, 0, stream>>>(Wdec, wdec_b, (J_ * EDEC) / 4);
    cvt_bf16<<<2560, 256, 0, stream>>>(Wout, wout_b, (V_ * J_) / 4);

    // 2) stage-1 projections (bias folded into LN)
    gemm_bt<<<dim3(J_ / 128, (T_ * B_) / 128), 256, 0, stream>>>(encin, wenc_b, eproj, nullptr, EENC, J_);
    gemm_bt<<<dim3(J_ / 128, (U_ * B_) / 128), 256, 0, stream>>>(decin, wdec_b, dproj, nullptr, EDEC, J_);

    // 3) LayerNorm (+bias +affine), transpose to [B, T/U, J], bf16
    ln_kernel<<<T_ * B_, 256, 0, stream>>>(eproj, benc, genc, beenc, encln, B_, T_);
    ln_kernel<<<U_ * B_, 256, 0, stream>>>(dproj, bdec, gdec, bedec, decln, B_, U_);

    // 4) joint = relu(enc + dec) materialized bf16 [B*T*U][J]
    joint_mat<<<(B_ * T_ * U_ * (J_ / 8)) / 256, 256, 0, stream>>>(encln, decln, joint);

    // 5) vocab projection: [65536, 640] x [640, 4096]^T + b_out -> d_out
    gemm_big<<<(B_ * T_ * U_ / 128) * (V_ / 128), 256, 0, stream>>>(joint, wout_b, out, bout);
}